// Round 9
// baseline (61.960 us; speedup 1.0000x reference)
//
#include <hip/hip_runtime.h>
#include <hip/hip_bf16.h>

// WaveletConv: Haar DWT -> 4x (64x64 channel mix) -> inverse Haar, fused.
// B=8, C=64, H=256, W=256. Subband grid 128x128.
// R9: barrier-free register-resident kernel. No LDS tile, no __syncthreads,
//     no DMA: each wave burst-issues 32x8B global loads for its own 2x2
//     patches (lanes coalesce to 128B segments; the 4 mt-waves of a block
//     share the same 16KB tile via L1/L2), Haar+cvt in registers, 8 MFMAs,
//     nt stores. Waves run fully independent -> no barrier convoy; per-CU
//     bytes in flight ~128KB >> R7's 32KB. Tests "convoy vs fabric ceiling".

using bf16x8 = __attribute__((ext_vector_type(8))) short;   // 8 bf16
using f32x4  = __attribute__((ext_vector_type(4))) float;   // MFMA acc
using f32x2  = __attribute__((ext_vector_type(2))) float;

__device__ inline unsigned short f2bf(float v) {
    __hip_bfloat16 h = __float2bfloat16(v);
    return __builtin_bit_cast(unsigned short, h);
}

// ---------------------------------------------------------------------------
// Prep kernel (64 blocks x 256 thr): bake per-lane MFMA A-fragments (scaled
// by 0.5 = Haar factor) and combined biases into d_ws.
//   afrag[((band*2+ks)*4+mt)*512 + lane*8 + i] =
//       bf16( 0.5 * W_band[o=16*mt+(lane&15)][c=32*ks+(lane>>4)*8+i] )
//   bcomb[d*64+o] = 0.5*(bLL + sH*bLH + sW*bHL + sH*sW*bHH), d=di*2+dj
// ---------------------------------------------------------------------------
__global__ __launch_bounds__(256) void wvc_prep(
    const float* __restrict__ wLL, const float* __restrict__ bLL,
    const float* __restrict__ wLH, const float* __restrict__ bLH,
    const float* __restrict__ wHL, const float* __restrict__ bHL,
    const float* __restrict__ wHH, const float* __restrict__ bHH,
    unsigned short* __restrict__ afrag, float* __restrict__ bcomb)
{
    const int idx  = blockIdx.x * 256 + threadIdx.x;  // 0..16383
    const int i    = idx & 7;
    const int lane = (idx >> 3) & 63;
    const int mt   = (idx >> 9) & 3;
    const int ks   = (idx >> 11) & 1;
    const int band = (idx >> 12) & 3;
    const float* Ws[4] = {wLL, wLH, wHL, wHH};
    const int o = mt * 16 + (lane & 15);
    const int c = ks * 32 + (lane >> 4) * 8 + i;
    afrag[idx] = f2bf(0.5f * Ws[band][o * 64 + c]);

    if (blockIdx.x == 0 && threadIdx.x < 64) {
        const int t = threadIdx.x;
        float b0 = bLL[t], b1 = bLH[t], b2 = bHL[t], b3 = bHH[t];
        bcomb[0 * 64 + t] = 0.5f * (b0 + b1 + b2 + b3);
        bcomb[1 * 64 + t] = 0.5f * (b0 + b1 - b2 - b3);
        bcomb[2 * 64 + t] = 0.5f * (b0 - b1 + b2 - b3);
        bcomb[3 * 64 + t] = 0.5f * (b0 - b1 - b2 + b3);
    }
}

// ---------------------------------------------------------------------------
// Main kernel. grid = 512 blocks x 256 threads (4 waves), 2 blocks/CU.
// Block blk: b = blk>>6, seg = (blk>>3)&7, hpg = blk&7.
// Wave = out-ch tile mt (0..3); all 4 waves share the same input patches
// (sites seg*16..+15) -> L1/L2 reuse x4. Loop t=0..15 over h-pairs
// hp = hpg*16+t. Per wave per tile: 32x 8B loads (burst), Haar+cvt, 8 MFMA,
// 8 nt 8B stores. No LDS, no barriers.
// ---------------------------------------------------------------------------
#define NT 16
__global__ __launch_bounds__(256, 2) void wvc_main(
    const float* __restrict__ x,
    const unsigned short* __restrict__ afrag_g,
    const float* __restrict__ bcomb,
    float* __restrict__ out)
{
    const int tid = threadIdx.x;
    const int l   = tid & 63;
    const int mt  = tid >> 6;            // 0..3: out-ch tile per wave
    const int blk = blockIdx.x;
    const int b   = blk >> 6;            // 0..7
    const int seg = (blk >> 3) & 7;      // 0..7: 16-site w segment
    const int hpg = blk & 7;             // 0..7: group of 16 h-pairs
    const int lg  = l >> 4;              // 0..3
    const int site = seg * 16 + (l & 15);

    // ---- A-fragments: 8 x bf16x8 (32 VGPR), persist ----
    const unsigned short* afb = afrag_g + (size_t)l * 8;
    bf16x8 a[4][2];  // [band][ks]
    #pragma unroll
    for (int bd = 0; bd < 4; ++bd)
        #pragma unroll
        for (int ks = 0; ks < 2; ++ks)
            a[bd][ks] = *(const bf16x8*)(
                afb + (size_t)((bd * 2 + ks) * 4 + mt) * 512);

    // ---- bias combos: 16 VGPR ----
    const int ob0 = mt * 16 + lg * 4;
    f32x4 bc0 = *(const f32x4*)(bcomb +   0 + ob0);
    f32x4 bc1 = *(const f32x4*)(bcomb +  64 + ob0);
    f32x4 bc2 = *(const f32x4*)(bcomb + 128 + ob0);
    f32x4 bc3 = *(const f32x4*)(bcomb + 192 + ob0);

    // per-lane bases: channel ch(ks,i) = ks*32 + lg*8 + i
    const float* xb = x + (size_t)b * 4194304 + (size_t)(lg * 8) * 65536
                        + (size_t)(hpg * 16) * 512 + 2 * site;
    float* obase = out + (size_t)b * 4194304 + (size_t)ob0 * 65536
                       + (size_t)(hpg * 16) * 512 + 2 * site;

    #pragma unroll
    for (int t = 0; t < NT; ++t) {
        // ---- burst: 32 x global_load_dwordx2, all issued before any use ----
        float2 p0[2][8], p1[2][8];   // [ks][i], rows h0 / h0+1
        #pragma unroll
        for (int ks = 0; ks < 2; ++ks)
            #pragma unroll
            for (int i = 0; i < 8; ++i) {
                const float* pp = xb + (size_t)(ks * 32 + i) * 65536
                                     + (size_t)t * 512;
                p0[ks][i] = *(const float2*)pp;          // row 2hp
                p1[ks][i] = *(const float2*)(pp + 256);  // row 2hp+1
            }
        __builtin_amdgcn_sched_barrier(0);   // pin burst-issue order

        // ---- Haar (0.5 folded into W) -> bf16 B-fragments ----
        bf16x8 bfr[4][2];  // [band][ks]
        #pragma unroll
        for (int ks = 0; ks < 2; ++ks)
            #pragma unroll
            for (int i = 0; i < 8; ++i) {
                float aa = p0[ks][i].x + p0[ks][i].y;
                float mm = p0[ks][i].x - p0[ks][i].y;
                float cc = p1[ks][i].x + p1[ks][i].y;
                float dd = p1[ks][i].x - p1[ks][i].y;
                bfr[0][ks][i] = (short)f2bf(aa + cc);
                bfr[1][ks][i] = (short)f2bf(aa - cc);
                bfr[2][ks][i] = (short)f2bf(mm + dd);
                bfr[3][ks][i] = (short)f2bf(mm - dd);
            }

        // ---- MFMA: 4 bands x 2 ks, K=64 complete per tile ----
        f32x4 acc[4];
        #pragma unroll
        for (int bd = 0; bd < 4; ++bd)
            acc[bd] = (f32x4){0.f, 0.f, 0.f, 0.f};
        #pragma unroll
        for (int bd = 0; bd < 4; ++bd)
            #pragma unroll
            for (int ks = 0; ks < 2; ++ks)
                acc[bd] = __builtin_amdgcn_mfma_f32_16x16x32_bf16(
                    a[bd][ks], bfr[bd][ks], acc[bd], 0, 0, 0);

        // ---- epilogue: inverse Haar recombine + bias, 8 nt f32x2 stores ----
        float* ob = obase + (size_t)t * 512;
        #pragma unroll
        for (int r = 0; r < 4; ++r) {
            float y0 = acc[0][r];  // LL
            float y1 = acc[1][r];  // LH (high-H)
            float y2 = acc[2][r];  // HL (high-W)
            float y3 = acc[3][r];  // HH
            float s01 = y0 + y1, d01 = y0 - y1;
            float s23 = y2 + y3, d23 = y2 - y3;
            f32x2 v0; v0[0] = 0.5f * (s01 + s23) + bc0[r];
                      v0[1] = 0.5f * (s01 - s23) + bc1[r];
            f32x2 v1; v1[0] = 0.5f * (d01 + d23) + bc2[r];
                      v1[1] = 0.5f * (d01 - d23) + bc3[r];
            float* po = ob + (size_t)r * 65536;
            __builtin_nontemporal_store(v0, (f32x2*)po);
            __builtin_nontemporal_store(v1, (f32x2*)(po + 256));
        }
        __builtin_amdgcn_sched_barrier(0);   // keep tile phases separated
    }
}

extern "C" void kernel_launch(void* const* d_in, const int* in_sizes, int n_in,
                              void* d_out, int out_size, void* d_ws, size_t ws_size,
                              hipStream_t stream) {
    const float* x   = (const float*)d_in[0];
    const float* wLL = (const float*)d_in[1];
    const float* bLL = (const float*)d_in[2];
    const float* wLH = (const float*)d_in[3];
    const float* bLH = (const float*)d_in[4];
    const float* wHL = (const float*)d_in[5];
    const float* bHL = (const float*)d_in[6];
    const float* wHH = (const float*)d_in[7];
    const float* bHH = (const float*)d_in[8];
    float* out = (float*)d_out;

    unsigned short* afrag = (unsigned short*)d_ws;   // 32768 B
    float* bcomb = (float*)((char*)d_ws + 32768);    // 1024 B

    wvc_prep<<<64, 256, 0, stream>>>(wLL, bLL, wLH, bLH, wHL, bHL, wHH, bHH,
                                     afrag, bcomb);
    wvc_main<<<512, 256, 0, stream>>>(x, afrag, bcomb, out);
}

// Round 10
// 51.935 us; speedup vs baseline: 1.1930x; 1.1930x over previous
//
#include <hip/hip_runtime.h>
#include <hip/hip_bf16.h>

// WaveletConv: Haar DWT -> 4x (64x64 channel mix) -> inverse Haar, fused.
// B=8, C=64, H=256, W=256. Subband grid 128x128.
// R10: R7 + depth-3 read pipeline (4 LDS buffers, 96KB of reads in flight
//      per CU nominal vs Little's-law need ~50KB), exact store-exclusion
//      vmcnt ledger. Everything else identical to R7 (best: 52.7us).

using bf16x8 = __attribute__((ext_vector_type(8))) short;   // 8 bf16
using f32x4  = __attribute__((ext_vector_type(4))) float;   // MFMA acc
using f32x2  = __attribute__((ext_vector_type(2))) float;

__device__ inline unsigned short f2bf(float v) {
    __hip_bfloat16 h = __float2bfloat16(v);
    return __builtin_bit_cast(unsigned short, h);
}

// ---------------------------------------------------------------------------
// Prep kernel (64 blocks x 256 thr): bake per-lane MFMA A-fragments (scaled
// by 0.5 = Haar factor) and combined biases into d_ws.
//   afrag[((band*2+ks)*4+mt)*512 + lane*8 + i] =
//       bf16( 0.5 * W_band[o=16*mt+(lane&15)][c=32*ks+(lane>>4)*8+i] )
//   bcomb[d*64+o] = 0.5*(bLL + sH*bLH + sW*bHL + sH*sW*bHH), d=di*2+dj
// ---------------------------------------------------------------------------
__global__ __launch_bounds__(256) void wvc_prep(
    const float* __restrict__ wLL, const float* __restrict__ bLL,
    const float* __restrict__ wLH, const float* __restrict__ bLH,
    const float* __restrict__ wHL, const float* __restrict__ bHL,
    const float* __restrict__ wHH, const float* __restrict__ bHH,
    unsigned short* __restrict__ afrag, float* __restrict__ bcomb)
{
    const int idx  = blockIdx.x * 256 + threadIdx.x;  // 0..16383
    const int i    = idx & 7;
    const int lane = (idx >> 3) & 63;
    const int mt   = (idx >> 9) & 3;
    const int ks   = (idx >> 11) & 1;
    const int band = (idx >> 12) & 3;
    const float* Ws[4] = {wLL, wLH, wHL, wHH};
    const int o = mt * 16 + (lane & 15);
    const int c = ks * 32 + (lane >> 4) * 8 + i;
    afrag[idx] = f2bf(0.5f * Ws[band][o * 64 + c]);

    if (blockIdx.x == 0 && threadIdx.x < 64) {
        const int t = threadIdx.x;
        float b0 = bLL[t], b1 = bLH[t], b2 = bHL[t], b3 = bHH[t];
        bcomb[0 * 64 + t] = 0.5f * (b0 + b1 + b2 + b3);
        bcomb[1 * 64 + t] = 0.5f * (b0 + b1 - b2 - b3);
        bcomb[2 * 64 + t] = 0.5f * (b0 - b1 + b2 - b3);
        bcomb[3 * 64 + t] = 0.5f * (b0 - b1 - b2 + b3);
    }
}

// ---------------------------------------------------------------------------
// Main kernel. grid = 256 blocks, 512 threads (8 waves), 1 block/CU.
// Block blk: b = blk>>5, jq = (blk>>3)&3, ih = blk&7; tiles t=0..15 at
// irow = ih*16+t (h0 = 2*irow), w0 = 64*jq (floats).
// Tile in LDS: 64 ch x 2 rows x 64 w f32; off(ch,row,w) =
//   ch*512 + (ch>>3)*32 + row*256 + w*4.   4 buffers (depth-3 prefetch).
// Wave wv (0..7): stages channels wv*8..wv*8+7 (4 DMAs of 2ch x 2rows x 256B);
//   computes sites sg*16..+15 (sg=wv&1) x out-ch mt*16..+15 (mt=wv>>1).
// Per tile per wave: 4 DMAs in, 8 MFMAs, 8 nt f32x2 stores out.
// vmcnt ledger at tile-t wait (DMA batch=4, store batch=8); outstanding
// issued after DMA(t): stores(t-1..t-3) + DMA(t+1..t+3):
//   t=0:12  t=1:20  t=2:28  steady:36  t=NT-3:32  t=NT-2:28  t=NT-1:24
// ---------------------------------------------------------------------------
#define NT 16
__global__ __launch_bounds__(512, 1) void wvc_main(
    const float* __restrict__ x,
    const unsigned short* __restrict__ afrag_g,
    const float* __restrict__ bcomb,
    float* __restrict__ out)
{
    __shared__ __align__(64) unsigned char lds_x[4][33024];  // 32KB + pads
    __shared__ __align__(16) float lds_bc[256];

    const int tid = threadIdx.x;
    const int l   = tid & 63;
    const int wv  = tid >> 6;          // 0..7
    const int blk = blockIdx.x;
    const int b   = blk >> 5;
    const int jq  = (blk >> 3) & 3;
    const int ih  = blk & 7;
    const int w0  = jq * 64;           // float offset in W

    const int sg   = wv & 1;
    const int mt   = wv >> 1;          // 0..3
    const int site = sg * 16 + (l & 15);   // 0..31
    const int lg   = l >> 4;

    if (tid < 256) lds_bc[tid] = bcomb[tid];

    // ---- A-fragments: load once, persist in registers (8 x bf16x8) ----
    const unsigned short* afb = afrag_g + (size_t)l * 8;
    bf16x8 a[4][2];  // [band][ks]
    #pragma unroll
    for (int bd = 0; bd < 4; ++bd)
        #pragma unroll
        for (int ks = 0; ks < 2; ++ks)
            a[bd][ks] = *(const bf16x8*)(
                afb + (size_t)((bd * 2 + ks) * 4 + mt) * 512);

    // ---- DMA bases: wave wv stages channels wv*8 .. wv*8+7 ----
    // DMA k covers channels (wv*8+2k, wv*8+2k+1); per-lane global source:
    //   ch += l>>5, row = (l>>4)&1, w = (l&15)*4 ; LDS dest = base + l*16.
    const float* xb = x + (size_t)b * 4194304
                        + (size_t)(wv * 8 + (l >> 5)) * 65536
                        + (size_t)((l >> 4) & 1) * 256 + w0 + (l & 15) * 4;
    const int lbo = wv * 4096 + wv * 32;   // LDS offset of wave's channels

    #define STAGE(s)                                                          \
    {                                                                         \
        const float* g = xb + (size_t)(ih * 16 + (s)) * 512;                  \
        unsigned char* lbn = &lds_x[(s) & 3][lbo];                            \
        _Pragma("unroll")                                                     \
        for (int k = 0; k < 4; ++k)                                           \
            __builtin_amdgcn_global_load_lds(                                 \
                (const __attribute__((address_space(1))) void*)(g + (size_t)(2 * k) * 65536), \
                (__attribute__((address_space(3))) void*)(lbn + k * 1024),    \
                16, 0, 0);                                                    \
    }

    // prologue: prefetch tiles 0,1,2 into bufs 0,1,2
    STAGE(0); STAGE(1); STAGE(2);
    asm volatile("s_waitcnt lgkmcnt(0)" ::: "memory");  // lds_bc visible

    #pragma unroll
    for (int t = 0; t < NT; ++t) {
        // issue tile t+3's DMAs FIRST, then counted wait for tile t
        if (t + 3 < NT) STAGE(t + 3);
        if (t == 0)            asm volatile("s_waitcnt vmcnt(12)" ::: "memory");
        else if (t == 1)       asm volatile("s_waitcnt vmcnt(20)" ::: "memory");
        else if (t == 2)       asm volatile("s_waitcnt vmcnt(28)" ::: "memory");
        else if (t + 3 < NT)   asm volatile("s_waitcnt vmcnt(36)" ::: "memory");
        else if (t + 2 < NT)   asm volatile("s_waitcnt vmcnt(32)" ::: "memory");
        else if (t + 1 < NT)   asm volatile("s_waitcnt vmcnt(28)" ::: "memory");
        else                   asm volatile("s_waitcnt vmcnt(24)" ::: "memory");
        __builtin_amdgcn_sched_barrier(0);
        __builtin_amdgcn_s_barrier();      // raw: prefetch stays in flight
        __builtin_amdgcn_sched_barrier(0);

        const unsigned char* bx = lds_x[t & 3];

        // ---- B-fragments: LDS x -> Haar (0.5 folded into W) -> bf16 ----
        bf16x8 bfr[4][2];  // [band][ks]
        #pragma unroll
        for (int ks = 0; ks < 2; ++ks) {
            float2 p0[8], p1[8];
            #pragma unroll
            for (int i = 0; i < 8; ++i) {
                const unsigned char* base =
                    bx + (size_t)(ks * 32 + lg * 8 + i) * 512
                       + (ks * 4 + lg) * 32 + site * 8;
                p0[i] = *(const float2*)(base);        // row h0
                p1[i] = *(const float2*)(base + 256);  // row h0+1
            }
            #pragma unroll
            for (int i = 0; i < 8; ++i) {
                float aa = p0[i].x + p0[i].y, mm = p0[i].x - p0[i].y;
                float cc = p1[i].x + p1[i].y, dd = p1[i].x - p1[i].y;
                bfr[0][ks][i] = (short)f2bf(aa + cc);
                bfr[1][ks][i] = (short)f2bf(aa - cc);
                bfr[2][ks][i] = (short)f2bf(mm + dd);
                bfr[3][ks][i] = (short)f2bf(mm - dd);
            }
        }

        // ---- MFMA: 4 bands x 2 ks, single mt per wave ----
        f32x4 acc[4];
        #pragma unroll
        for (int bd = 0; bd < 4; ++bd)
            acc[bd] = (f32x4){0.f, 0.f, 0.f, 0.f};
        #pragma unroll
        for (int bd = 0; bd < 4; ++bd)
            #pragma unroll
            for (int ks = 0; ks < 2; ++ks)
                acc[bd] = __builtin_amdgcn_mfma_f32_16x16x32_bf16(
                    a[bd][ks], bfr[bd][ks], acc[bd], 0, 0, 0);

        // ---- epilogue: inverse Haar recombine + bias, 8 nt f32x2 stores ----
        const int h0 = (ih * 16 + t) * 2;
        float* ob = out + (size_t)b * 4194304 + (size_t)h0 * 256 + w0 + 2 * site;
        const int ob0 = mt * 16 + lg * 4;
        f32x4 bc0 = *(const f32x4*)(&lds_bc[  0 + ob0]);
        f32x4 bc1 = *(const f32x4*)(&lds_bc[ 64 + ob0]);
        f32x4 bc2 = *(const f32x4*)(&lds_bc[128 + ob0]);
        f32x4 bc3 = *(const f32x4*)(&lds_bc[192 + ob0]);
        #pragma unroll
        for (int r = 0; r < 4; ++r) {
            float y0 = acc[0][r];  // LL
            float y1 = acc[1][r];  // LH (high-H)
            float y2 = acc[2][r];  // HL (high-W)
            float y3 = acc[3][r];  // HH
            float s01 = y0 + y1, d01 = y0 - y1;
            float s23 = y2 + y3, d23 = y2 - y3;
            f32x2 v0; v0[0] = 0.5f * (s01 + s23) + bc0[r];
                      v0[1] = 0.5f * (s01 - s23) + bc1[r];
            f32x2 v1; v1[0] = 0.5f * (d01 + d23) + bc2[r];
                      v1[1] = 0.5f * (d01 - d23) + bc3[r];
            float* po = ob + (size_t)(ob0 + r) * 65536;
            __builtin_nontemporal_store(v0, (f32x2*)po);
            __builtin_nontemporal_store(v1, (f32x2*)(po + 256));
        }

        __builtin_amdgcn_sched_barrier(0);
        __builtin_amdgcn_s_barrier();   // all waves done reading buf[t&3]
        __builtin_amdgcn_sched_barrier(0);  // before iter t+1 restages it
    }
    #undef STAGE
}

extern "C" void kernel_launch(void* const* d_in, const int* in_sizes, int n_in,
                              void* d_out, int out_size, void* d_ws, size_t ws_size,
                              hipStream_t stream) {
    const float* x   = (const float*)d_in[0];
    const float* wLL = (const float*)d_in[1];
    const float* bLL = (const float*)d_in[2];
    const float* wLH = (const float*)d_in[3];
    const float* bLH = (const float*)d_in[4];
    const float* wHL = (const float*)d_in[5];
    const float* bHL = (const float*)d_in[6];
    const float* wHH = (const float*)d_in[7];
    const float* bHH = (const float*)d_in[8];
    float* out = (float*)d_out;

    unsigned short* afrag = (unsigned short*)d_ws;   // 32768 B
    float* bcomb = (float*)((char*)d_ws + 32768);    // 1024 B

    wvc_prep<<<64, 256, 0, stream>>>(wLL, bLL, wLH, bLH, wHL, bHL, wHH, bHH,
                                     afrag, bcomb);
    wvc_main<<<256, 512, 0, stream>>>(x, afrag, bcomb, out);
}